// Round 10
// baseline (104.922 us; speedup 1.0000x reference)
//
#include <hip/hip_runtime.h>
#include <math.h>

#define B_N 524288
#define C_N 40
constexpr int BLOCK = 320;          // 5 waves
constexpr int GRID  = 1024;         // 4 blocks/CU, single round
constexpr int NWAVE = BLOCK / 64;   // 5
constexpr int VEC   = 4;
constexpr int NSLOT = 4;            // LDS slots per wave (depth-3 prefetch)
constexpr int STEPS = 16;           // GRID*BLOCK*VEC*STEPS == B_N*C_N exactly
constexpr int NREP  = 32;

typedef float f32x4 __attribute__((ext_vector_type(4)));

__device__ __forceinline__ void vmwait(int n) {    // n is constant after unroll
    switch (n) {
    case 4:  asm volatile("s_waitcnt vmcnt(4)" ::: "memory"); break;
    case 2:  asm volatile("s_waitcnt vmcnt(2)" ::: "memory"); break;
    default: asm volatile("s_waitcnt vmcnt(0)" ::: "memory"); break;
    }
    __builtin_amdgcn_sched_barrier(0);
}
__device__ __forceinline__ void lgkm0() {
    asm volatile("s_waitcnt lgkmcnt(0)" ::: "memory");
    __builtin_amdgcn_sched_barrier(0);
}

// Per-wave private DMA pipeline: global_load_lds has NO dest VGPR, so the
// compiler cannot serialize it; vmcnt tracks completion in hardware. The
// only vmcnt events in the loop are these DMAs -> counted waits are sound.
__global__ __launch_bounds__(BLOCK, 5) void bdl_accum(
    const float* __restrict__ pred, const float* __restrict__ tgt,
    float* __restrict__ gacc)
{
    constexpr float  LN9    = 2.1972245773362196f;
    constexpr size_t STRIDE = (size_t)GRID * BLOCK * VEC;   // 1,310,720 (== 0 mod 40)

    // 5 waves x 4 slots x {pred,tgt} x 256 floats (1KB each) = 40KB/block
    __shared__ __align__(16) float smem[NWAVE][NSLOT][2][256];

    float cntp[VEC] = {0.f,0.f,0.f,0.f};
    float sall[VEC] = {0.f,0.f,0.f,0.f};
    float spos[VEC] = {0.f,0.f,0.f,0.f};
    float spe[VEC]  = {0.f,0.f,0.f,0.f};
    float sne[VEC]  = {0.f,0.f,0.f,0.f};

    const int tid = threadIdx.x;
    const int wv  = tid >> 6;          // wave-uniform
    const int ln  = tid & 63;

    // per-lane element index; lane's 16B lands at LDS base + lane*16
    const size_t base = (size_t)blockIdx.x * (BLOCK * VEC) + (size_t)tid * VEC;

    auto issue = [&](int step) {       // step is compile-time under unroll
        const int slot = step & (NSLOT - 1);
        const float* gp = pred + base + (size_t)step * STRIDE;
        const float* gt = tgt  + base + (size_t)step * STRIDE;
        __builtin_amdgcn_global_load_lds(
            (const __attribute__((address_space(1))) void*)gp,
            (__attribute__((address_space(3))) void*)&smem[wv][slot][0][0],
            16, 0, 0);
        __builtin_amdgcn_global_load_lds(
            (const __attribute__((address_space(1))) void*)gt,
            (__attribute__((address_space(3))) void*)&smem[wv][slot][1][0],
            16, 0, 0);
    };

    issue(0); issue(1); issue(2);      // prologue: 6 DMAs outstanding

    #pragma unroll
    for (int k = 0; k < STEPS; ++k) {
        // step k's 2 DMAs are the oldest; keep the newer ones in flight
        vmwait(k < STEPS - 2 ? 4 : (k == STEPS - 2 ? 2 : 0));
        const int slot = k & (NSLOT - 1);
        const f32x4 pv = *reinterpret_cast<const f32x4*>(&smem[wv][slot][0][ln * 4]);
        const f32x4 tv = *reinterpret_cast<const f32x4*>(&smem[wv][slot][1][ln * 4]);
        lgkm0();                        // data in regs; slot reusable
        if (k + 3 < STEPS) issue(k + 3);

        #pragma unroll
        for (int j = 0; j < VEC; ++j) {
            const float x  = pv[j];
            const float t  = tv[j];
            const float e  = __expf(-fabsf(x));
            const float sp_ = __logf(1.f + e);            // softplus(-|x|)
            const float bce = sp_ + fmaxf(x, 0.f) - x * t;
            const float bpos = (x >  LN9) ? bce : 0.f;    // easy positive
            const float bneg = (x < -LN9) ? bce : 0.f;    // easy negative
            cntp[j] += t;
            sall[j] += bce;
            spos[j]  = fmaf(t, bce,   spos[j]);
            spe[j]   = fmaf(t, bpos,  spe[j]);            // t * easy-pos
            sne[j]   = fmaf(-t, bneg, sne[j] + bneg);     // (1-t) * easy-neg
        }
    }

    __syncthreads();                    // repurpose staging LDS for reduction
    float* lacc = &smem[0][0][0][0];
    if (tid < C_N * 5) lacc[tid] = 0.f;
    __syncthreads();
    const int c0 = (tid * VEC) % C_N;   // constant classes per thread
    #pragma unroll
    for (int j = 0; j < VEC; ++j) {
        float* a = &lacc[(c0 + j) * 5];
        atomicAdd(a + 0, cntp[j]);
        atomicAdd(a + 1, sall[j]);
        atomicAdd(a + 2, spos[j]);
        atomicAdd(a + 3, spe[j]);
        atomicAdd(a + 4, sne[j]);
    }
    __syncthreads();
    if (tid < C_N * 5)
        atomicAdd(&gacc[(blockIdx.x % NREP) * (C_N * 5) + tid], lacc[tid]);
}

__global__ void bdl_final(const float* __restrict__ gacc, float* __restrict__ out)
{
    __shared__ float acc[C_N * 5];
    const int tid = threadIdx.x;
    if (tid < C_N * 5) {
        float s = 0.f;
        #pragma unroll
        for (int r = 0; r < NREP; ++r) s += gacc[r * (C_N * 5) + tid];
        acc[tid] = s;
    }
    __syncthreads();
    if (tid == 0) {
        const float Bf  = (float)B_N;
        const float bal = 0.5f * Bf;               // PROP * batch
        float tot = 0.f;
        for (int c = 0; c < C_N; ++c) {
            const float cntp = acc[c * 5 + 0];
            const float sall = acc[c * 5 + 1];
            const float sp   = acc[c * 5 + 2];
            const float spe  = acc[c * 5 + 3];
            const float sne  = acc[c * 5 + 4];
            const float sn   = sall - sp;
            const bool posmaj = (cntp >= bal);     // pos_gt; else neg_gt
            const float nmaj = posmaj ? cntp : (Bf - cntp);
            const float nmin = Bf - nmaj;
            const float smaj = posmaj ? (sp - spe) : (sn - sne);
            const float smin = posmaj ? sn : sp;
            const float wmaj = bal / fmaxf(nmaj, 1.f);
            const float wmin = (nmin > 0.f) ? ((Bf - bal) / fmaxf(nmin, 1.f)) : 1.f;
            tot += smaj * wmaj + smin * wmin;
        }
        out[0] = tot / (Bf * (float)C_N);
    }
}

extern "C" void kernel_launch(void* const* d_in, const int* in_sizes, int n_in,
                              void* d_out, int out_size, void* d_ws, size_t ws_size,
                              hipStream_t stream) {
    const float* pred = (const float*)d_in[0];
    const float* tgt  = (const float*)d_in[1];
    float* gacc = (float*)d_ws;                       // NREP*200 floats = 25.6 KB
    hipMemsetAsync(gacc, 0, NREP * C_N * 5 * sizeof(float), stream);
    bdl_accum<<<GRID, BLOCK, 0, stream>>>(pred, tgt, gacc);
    bdl_final<<<1, 256, 0, stream>>>(gacc, (float*)d_out);
}